// Round 2
// baseline (18951.044 us; speedup 1.0000x reference)
//
#include <hip/hip_runtime.h>

// GRU: B=32, S=512, D=1024, H=1024
// out = concat(output[B,S,H], h_last[B,H]) f32
#define B_  32
#define S_  512
#define D_  1024
#define H_  1024
#define G3  3072

typedef __attribute__((ext_vector_type(8))) short  short8;   // 8 x bf16 (4 VGPR)
typedef __attribute__((ext_vector_type(4))) float  floatx4;  // MFMA C/D

__device__ __forceinline__ unsigned short f2bf(float f) {
    unsigned int u = __builtin_bit_cast(unsigned int, f);
    u = (u + 0x7FFFu + ((u >> 16) & 1u)) >> 16;
    return (unsigned short)u;
}
__device__ __forceinline__ float bf2f(unsigned short h) {
    unsigned int u = ((unsigned int)h) << 16;
    return __builtin_bit_cast(float, u);
}
// fast sigmoid/tanh via v_exp_f32 + v_rcp_f32 (saturate correctly at +/-inf)
__device__ __forceinline__ float fsigmoid(float x) {
    float e = __builtin_amdgcn_exp2f(-1.4426950408889634f * x);
    return __builtin_amdgcn_rcpf(1.f + e);
}
__device__ __forceinline__ float ftanh(float x) {
    float e = __builtin_amdgcn_exp2f(2.8853900817779268f * x);
    return 1.f - 2.f * __builtin_amdgcn_rcpf(e + 1.f);
}

// ---------------------------------------------------------------------------
// Kernel 0: convert weights f32->bf16 (W_hh hi/lo split), zero h + counters
// ---------------------------------------------------------------------------
__global__ __launch_bounds__(256) void convert_kernel(
    const float* __restrict__ wih, const float* __restrict__ whh,
    unsigned short* __restrict__ wih_h,
    unsigned short* __restrict__ whh_h, unsigned short* __restrict__ whh_l,
    unsigned short* __restrict__ hbuf /* 131072 ushorts */,
    int* __restrict__ cnt /* 16384 ints */) {
    int tid = blockIdx.x * 256 + threadIdx.x;   // 786432 threads
    int i4 = tid * 4;
    if (i4 < 3145728) {
        float4 w = *(const float4*)(wih + i4);
        ushort4 o;
        o.x = f2bf(w.x); o.y = f2bf(w.y); o.z = f2bf(w.z); o.w = f2bf(w.w);
        *(ushort4*)(wih_h + i4) = o;

        float4 v = *(const float4*)(whh + i4);
        ushort4 h;
        h.x = f2bf(v.x); h.y = f2bf(v.y); h.z = f2bf(v.z); h.w = f2bf(v.w);
        ushort4 l;
        l.x = f2bf(v.x - bf2f(h.x)); l.y = f2bf(v.y - bf2f(h.y));
        l.z = f2bf(v.z - bf2f(h.z)); l.w = f2bf(v.w - bf2f(h.w));
        *(ushort4*)(whh_h + i4) = h;
        *(ushort4*)(whh_l + i4) = l;
    }
    if (tid < 32768) {  // zero both h ping-pong buffers (hi+lo planes)
        ushort4 z; z.x = z.y = z.z = z.w = 0;
        *(ushort4*)(hbuf + tid * 4) = z;
    }
    if (tid < 4096) {   // zero step counters (2 mt-groups x 512 steps x 16 pad)
        int4 z4; z4.x = z4.y = z4.z = z4.w = 0;
        *(int4*)(cnt + tid * 4) = z4;
    }
}

// ---------------------------------------------------------------------------
// Kernel 1: gi = feats @ W_ih^T + bias_ih   -> bf16 [B*S][3H]
// 128x128 tile, BK=32, 4 waves 2x2, mfma_f32_16x16x32_bf16
// ---------------------------------------------------------------------------
#define BM 128
#define BN 128
#define BK 32
#define LDA 40  // padded LDS row: 80B stride -> conflict-free b128 reads

__global__ __launch_bounds__(256, 2) void gi_gemm(
    const float* __restrict__ feats,
    const unsigned short* __restrict__ wih_h,
    const float* __restrict__ bias_ih,
    unsigned short* __restrict__ gi) {
    __shared__ unsigned short As[BM * LDA];
    __shared__ unsigned short Bs[BN * LDA];

    int bx = blockIdx.x;
    int nb = bx % (G3 / BN);          // 24
    int mb = bx / (G3 / BN);          // 128
    int m0 = mb * BM, n0 = nb * BN;
    int tid = threadIdx.x;
    int lane = tid & 63, wave = tid >> 6;
    int quad = lane >> 4, l15 = lane & 15;
    int wm = (wave >> 1) * 64, wn = (wave & 1) * 64;

    floatx4 acc[4][4];
#pragma unroll
    for (int i = 0; i < 4; ++i)
#pragma unroll
        for (int j = 0; j < 4; ++j) acc[i][j] = (floatx4){0.f, 0.f, 0.f, 0.f};

    float bias[4];
#pragma unroll
    for (int j = 0; j < 4; ++j) bias[j] = bias_ih[n0 + wn + j * 16 + l15];

    int srow = tid >> 1, shalf = tid & 1;
    const float* aptr = feats + (size_t)(m0 + srow) * D_ + shalf * 16;
    const unsigned short* bptr = wih_h + (size_t)(n0 + srow) * D_ + shalf * 16;
    unsigned short* as = As + srow * LDA + shalf * 16;
    unsigned short* bs = Bs + srow * LDA + shalf * 16;

    for (int kt = 0; kt < D_ / BK; ++kt) {
        int k0 = kt * BK;
        float4 a0 = *(const float4*)(aptr + k0);
        float4 a1 = *(const float4*)(aptr + k0 + 4);
        float4 a2 = *(const float4*)(aptr + k0 + 8);
        float4 a3 = *(const float4*)(aptr + k0 + 12);
        uint4 bA = *(const uint4*)(bptr + k0);
        uint4 bB = *(const uint4*)(bptr + k0 + 8);

        union { unsigned short u16[16]; uint4 v[2]; } pk;
        pk.u16[0] = f2bf(a0.x);  pk.u16[1] = f2bf(a0.y);
        pk.u16[2] = f2bf(a0.z);  pk.u16[3] = f2bf(a0.w);
        pk.u16[4] = f2bf(a1.x);  pk.u16[5] = f2bf(a1.y);
        pk.u16[6] = f2bf(a1.z);  pk.u16[7] = f2bf(a1.w);
        pk.u16[8] = f2bf(a2.x);  pk.u16[9] = f2bf(a2.y);
        pk.u16[10] = f2bf(a2.z); pk.u16[11] = f2bf(a2.w);
        pk.u16[12] = f2bf(a3.x); pk.u16[13] = f2bf(a3.y);
        pk.u16[14] = f2bf(a3.z); pk.u16[15] = f2bf(a3.w);

        *(uint4*)as = pk.v[0];
        *(uint4*)(as + 8) = pk.v[1];
        *(uint4*)bs = bA;
        *(uint4*)(bs + 8) = bB;
        __syncthreads();

        short8 af[4], bf[4];
#pragma unroll
        for (int i = 0; i < 4; ++i)
            af[i] = *(const short8*)(As + (wm + i * 16 + l15) * LDA + quad * 8);
#pragma unroll
        for (int j = 0; j < 4; ++j)
            bf[j] = *(const short8*)(Bs + (wn + j * 16 + l15) * LDA + quad * 8);
#pragma unroll
        for (int i = 0; i < 4; ++i)
#pragma unroll
            for (int j = 0; j < 4; ++j)
                acc[i][j] = __builtin_amdgcn_mfma_f32_16x16x32_bf16(
                    af[i], bf[j], acc[i][j], 0, 0, 0);
        __syncthreads();
    }

#pragma unroll
    for (int i = 0; i < 4; ++i)
#pragma unroll
        for (int j = 0; j < 4; ++j)
#pragma unroll
            for (int r = 0; r < 4; ++r) {
                int m = m0 + wm + i * 16 + quad * 4 + r;
                int n = n0 + wn + j * 16 + l15;
                gi[(size_t)m * G3 + n] = f2bf(acc[i][j][r] + bias[j]);
            }
}

// ---------------------------------------------------------------------------
// Kernel 2: persistent recurrence with per-(mt,t) flag sync (no grid.sync).
// 128 blocks = 64 jg (16 h-cols) x 2 mt (16 batch rows); 512 thr = 8 waves,
// wave = K-slice of 128. W_hh hi/lo frags in registers for all 512 steps.
// Producer: h stores -> threadfence -> atomicAdd(cnt[mt][t]) [release,agent].
// Consumer: all threads spin-acquire on cnt[mt][t-1]==64.
// Two mt groups are fully independent pipelines.
// ---------------------------------------------------------------------------
__global__ __launch_bounds__(512, 2) void gru_rec(
    const unsigned short* __restrict__ gi,
    const unsigned short* __restrict__ whh_h,
    const unsigned short* __restrict__ whh_l,
    const float* __restrict__ bias_hh,
    unsigned short* __restrict__ hbuf,  // [2][2][32][1024]
    int* __restrict__ cnt,              // [2*512*16]
    float* __restrict__ out) {
    __shared__ floatx4 parts[8][3][64];  // 24 KB

    int jg = blockIdx.x >> 1, mt = blockIdx.x & 1;
    int tid = threadIdx.x;
    int ks = tid >> 6, lane = tid & 63;
    int quad = lane >> 4, l15 = lane & 15;
    int j = jg * 16 + l15;

    // preload W_hh fragments (hi+lo): 3 gates x 4 ksteps x 16B = 96 VGPRs
    short8 wfh[3][4], wfl[3][4];
#pragma unroll
    for (int g = 0; g < 3; ++g)
#pragma unroll
        for (int ki = 0; ki < 4; ++ki) {
            size_t off = (size_t)(g * H_ + j) * H_ + ks * 128 + ki * 32 + quad * 8;
            wfh[g][ki] = *(const short8*)(whh_h + off);
            wfl[g][ki] = *(const short8*)(whh_l + off);
        }

    float bhh[3] = {0.f, 0.f, 0.f};
    float hreg[4] = {0.f, 0.f, 0.f, 0.f};
    if (ks == 0) {
#pragma unroll
        for (int g = 0; g < 3; ++g) bhh[g] = bias_hh[g * H_ + j];
    }

    const int arow = mt * 16 + l15;
    const int kbase = ks * 128 + quad * 8;
    int* const cbase = cnt + mt * 512 * 16;

    for (int t = 0; t < S_; ++t) {
        // gi prefetch (wave0) — independent of h, issued before the spin
        unsigned short giu[3][4];
        if (ks == 0) {
#pragma unroll
            for (int g = 0; g < 3; ++g)
#pragma unroll
                for (int r = 0; r < 4; ++r) {
                    int b = mt * 16 + quad * 4 + r;
                    giu[g][r] = gi[((size_t)b * S_ + t) * G3 + g * H_ + j];
                }
        }

        // wait for all 64 producer blocks of this mt group to finish step t-1
        if (t > 0) {
            const int* flag = cbase + (t - 1) * 16;
            while (__hip_atomic_load(flag, __ATOMIC_ACQUIRE,
                                     __HIP_MEMORY_SCOPE_AGENT) < 64) {}
        }

        const unsigned short* hc = hbuf + (size_t)(t & 1) * 65536;
        unsigned short* hn = hbuf + (size_t)((t & 1) ^ 1) * 65536;

        short8 ah[4], al[4];
#pragma unroll
        for (int ki = 0; ki < 4; ++ki) {
            const unsigned short* p = hc + arow * H_ + kbase + ki * 32;
            ah[ki] = *(const short8*)(p);
            al[ki] = *(const short8*)(p + 32768);
        }

        floatx4 acc[3];
#pragma unroll
        for (int g = 0; g < 3; ++g) acc[g] = (floatx4){0.f, 0.f, 0.f, 0.f};
#pragma unroll
        for (int ki = 0; ki < 4; ++ki)
#pragma unroll
            for (int g = 0; g < 3; ++g) {
                acc[g] = __builtin_amdgcn_mfma_f32_16x16x32_bf16(ah[ki], wfh[g][ki], acc[g], 0, 0, 0);
                acc[g] = __builtin_amdgcn_mfma_f32_16x16x32_bf16(ah[ki], wfl[g][ki], acc[g], 0, 0, 0);
                acc[g] = __builtin_amdgcn_mfma_f32_16x16x32_bf16(al[ki], wfh[g][ki], acc[g], 0, 0, 0);
            }
#pragma unroll
        for (int g = 0; g < 3; ++g) parts[ks][g][lane] = acc[g];
        __syncthreads();
        // waves 1..7 may proceed to next t; they are gated by the spin, which
        // is released only after wave0 has consumed `parts` (atomic comes last)

        float hy[4];
        if (ks == 0) {
            floatx4 gh[3];
#pragma unroll
            for (int g = 0; g < 3; ++g) {
                floatx4 s = parts[0][g][lane];
#pragma unroll
                for (int w = 1; w < 8; ++w) s += parts[w][g][lane];
                gh[g] = s;
            }
#pragma unroll
            for (int r = 0; r < 4; ++r) {
                int b = mt * 16 + quad * 4 + r;
                float rg = fsigmoid(bf2f(giu[0][r]) + gh[0][r] + bhh[0]);
                float zg = fsigmoid(bf2f(giu[1][r]) + gh[1][r] + bhh[1]);
                float ng = ftanh(bf2f(giu[2][r]) + rg * (gh[2][r] + bhh[2]));
                float h = ng + zg * (hreg[r] - ng);
                hreg[r] = h;
                hy[r] = h;
                unsigned short hh = f2bf(h);
                hn[b * H_ + j] = hh;
                hn[32768 + b * H_ + j] = f2bf(h - bf2f(hh));
            }
            __threadfence();  // make h stores agent-visible before the flag
        }
        if (tid == 0)
            __hip_atomic_fetch_add(cbase + t * 16, 1, __ATOMIC_RELEASE,
                                   __HIP_MEMORY_SCOPE_AGENT);
        // out stores off the critical path (not part of the sync protocol)
        if (ks == 0) {
#pragma unroll
            for (int r = 0; r < 4; ++r) {
                int b = mt * 16 + quad * 4 + r;
                out[((size_t)b * S_ + t) * H_ + j] = hy[r];
                if (t == S_ - 1)
                    out[(size_t)B_ * S_ * H_ + (size_t)b * H_ + j] = hy[r];
            }
        }
    }
}

// ---------------------------------------------------------------------------
extern "C" void kernel_launch(void* const* d_in, const int* in_sizes, int n_in,
                              void* d_out, int out_size, void* d_ws, size_t ws_size,
                              hipStream_t stream) {
    const float* feats = (const float*)d_in[0];
    const float* wih   = (const float*)d_in[1];
    const float* whh   = (const float*)d_in[2];
    const float* bih   = (const float*)d_in[3];
    const float* bhh   = (const float*)d_in[4];
    float* out = (float*)d_out;

    // ws layout (ushorts): wih_h | whh_h | whh_l | gi | hbuf | cnt
    unsigned short* wih_h = (unsigned short*)d_ws;
    unsigned short* whh_h = wih_h + (size_t)3145728;
    unsigned short* whh_l = whh_h + (size_t)3145728;
    unsigned short* gi    = whh_l + (size_t)3145728;
    unsigned short* hbuf  = gi + (size_t)16384 * G3;
    int*            cnt   = (int*)(hbuf + 131072);

    hipLaunchKernelGGL(convert_kernel, dim3(3072), dim3(256), 0, stream,
                       wih, whh, wih_h, whh_h, whh_l, hbuf, cnt);
    hipLaunchKernelGGL(gi_gemm, dim3(3072), dim3(256), 0, stream,
                       feats, wih_h, bih, gi);

    void* args[] = {(void*)&gi, (void*)&whh_h, (void*)&whh_l,
                    (void*)&bhh, (void*)&hbuf, (void*)&cnt, (void*)&out};
    hipLaunchCooperativeKernel((const void*)gru_rec, dim3(128), dim3(512),
                               args, 0, stream);
}

// Round 3
// 8240.479 us; speedup vs baseline: 2.2998x; 2.2998x over previous
//
#include <hip/hip_runtime.h>

// GRU: B=32, S=512, D=1024, H=1024
// out = concat(output[B,S,H], h_last[B,H]) f32
#define B_  32
#define S_  512
#define D_  1024
#define H_  1024
#define G3  3072

typedef __attribute__((ext_vector_type(8))) short  short8;   // 8 x bf16 (4 VGPR)
typedef __attribute__((ext_vector_type(4))) float  floatx4;  // MFMA C/D

__device__ __forceinline__ unsigned short f2bf(float f) {
    unsigned int u = __builtin_bit_cast(unsigned int, f);
    u = (u + 0x7FFFu + ((u >> 16) & 1u)) >> 16;
    return (unsigned short)u;
}
__device__ __forceinline__ float bf2f(unsigned short h) {
    unsigned int u = ((unsigned int)h) << 16;
    return __builtin_bit_cast(float, u);
}
// fast sigmoid/tanh via v_exp_f32 + v_rcp_f32 (saturate correctly at +/-inf)
__device__ __forceinline__ float fsigmoid(float x) {
    float e = __builtin_amdgcn_exp2f(-1.4426950408889634f * x);
    return __builtin_amdgcn_rcpf(1.f + e);
}
__device__ __forceinline__ float ftanh(float x) {
    float e = __builtin_amdgcn_exp2f(2.8853900817779268f * x);
    return 1.f - 2.f * __builtin_amdgcn_rcpf(e + 1.f);
}

// ---------------------------------------------------------------------------
// Kernel 0: convert weights f32->bf16 (W_hh hi/lo split), zero h + flags
// ---------------------------------------------------------------------------
__global__ __launch_bounds__(256) void convert_kernel(
    const float* __restrict__ wih, const float* __restrict__ whh,
    unsigned short* __restrict__ wih_h,
    unsigned short* __restrict__ whh_h, unsigned short* __restrict__ whh_l,
    unsigned short* __restrict__ hbuf /* 131072 ushorts */,
    int* __restrict__ cnt /* 128 ints: [mt][jg] flags */) {
    int tid = blockIdx.x * 256 + threadIdx.x;   // 786432 threads
    int i4 = tid * 4;
    if (i4 < 3145728) {
        float4 w = *(const float4*)(wih + i4);
        ushort4 o;
        o.x = f2bf(w.x); o.y = f2bf(w.y); o.z = f2bf(w.z); o.w = f2bf(w.w);
        *(ushort4*)(wih_h + i4) = o;

        float4 v = *(const float4*)(whh + i4);
        ushort4 h;
        h.x = f2bf(v.x); h.y = f2bf(v.y); h.z = f2bf(v.z); h.w = f2bf(v.w);
        ushort4 l;
        l.x = f2bf(v.x - bf2f(h.x)); l.y = f2bf(v.y - bf2f(h.y));
        l.z = f2bf(v.z - bf2f(h.z)); l.w = f2bf(v.w - bf2f(h.w));
        *(ushort4*)(whh_h + i4) = h;
        *(ushort4*)(whh_l + i4) = l;
    }
    if (tid < 32768) {  // zero both h ping-pong buffers (hi+lo planes)
        ushort4 z; z.x = z.y = z.z = z.w = 0;
        *(ushort4*)(hbuf + tid * 4) = z;
    }
    if (tid < 32) {     // zero the 128 per-producer step flags
        int4 z4; z4.x = z4.y = z4.z = z4.w = 0;
        *(int4*)(cnt + tid * 4) = z4;
    }
}

// ---------------------------------------------------------------------------
// Kernel 1: gi = feats @ W_ih^T + bias_ih   -> bf16 [B*S][3H]
// 128x128 tile, BK=32, 4 waves 2x2, mfma_f32_16x16x32_bf16
// ---------------------------------------------------------------------------
#define BM 128
#define BN 128
#define BK 32
#define LDA 40  // padded LDS row: 80B stride -> conflict-free b128 reads

__global__ __launch_bounds__(256, 2) void gi_gemm(
    const float* __restrict__ feats,
    const unsigned short* __restrict__ wih_h,
    const float* __restrict__ bias_ih,
    unsigned short* __restrict__ gi) {
    __shared__ unsigned short As[BM * LDA];
    __shared__ unsigned short Bs[BN * LDA];

    int bx = blockIdx.x;
    int nb = bx % (G3 / BN);          // 24
    int mb = bx / (G3 / BN);          // 128
    int m0 = mb * BM, n0 = nb * BN;
    int tid = threadIdx.x;
    int lane = tid & 63, wave = tid >> 6;
    int quad = lane >> 4, l15 = lane & 15;
    int wm = (wave >> 1) * 64, wn = (wave & 1) * 64;

    floatx4 acc[4][4];
#pragma unroll
    for (int i = 0; i < 4; ++i)
#pragma unroll
        for (int j = 0; j < 4; ++j) acc[i][j] = (floatx4){0.f, 0.f, 0.f, 0.f};

    float bias[4];
#pragma unroll
    for (int j = 0; j < 4; ++j) bias[j] = bias_ih[n0 + wn + j * 16 + l15];

    int srow = tid >> 1, shalf = tid & 1;
    const float* aptr = feats + (size_t)(m0 + srow) * D_ + shalf * 16;
    const unsigned short* bptr = wih_h + (size_t)(n0 + srow) * D_ + shalf * 16;
    unsigned short* as = As + srow * LDA + shalf * 16;
    unsigned short* bs = Bs + srow * LDA + shalf * 16;

    for (int kt = 0; kt < D_ / BK; ++kt) {
        int k0 = kt * BK;
        float4 a0 = *(const float4*)(aptr + k0);
        float4 a1 = *(const float4*)(aptr + k0 + 4);
        float4 a2 = *(const float4*)(aptr + k0 + 8);
        float4 a3 = *(const float4*)(aptr + k0 + 12);
        uint4 bA = *(const uint4*)(bptr + k0);
        uint4 bB = *(const uint4*)(bptr + k0 + 8);

        union { unsigned short u16[16]; uint4 v[2]; } pk;
        pk.u16[0] = f2bf(a0.x);  pk.u16[1] = f2bf(a0.y);
        pk.u16[2] = f2bf(a0.z);  pk.u16[3] = f2bf(a0.w);
        pk.u16[4] = f2bf(a1.x);  pk.u16[5] = f2bf(a1.y);
        pk.u16[6] = f2bf(a1.z);  pk.u16[7] = f2bf(a1.w);
        pk.u16[8] = f2bf(a2.x);  pk.u16[9] = f2bf(a2.y);
        pk.u16[10] = f2bf(a2.z); pk.u16[11] = f2bf(a2.w);
        pk.u16[12] = f2bf(a3.x); pk.u16[13] = f2bf(a3.y);
        pk.u16[14] = f2bf(a3.z); pk.u16[15] = f2bf(a3.w);

        *(uint4*)as = pk.v[0];
        *(uint4*)(as + 8) = pk.v[1];
        *(uint4*)bs = bA;
        *(uint4*)(bs + 8) = bB;
        __syncthreads();

        short8 af[4], bf[4];
#pragma unroll
        for (int i = 0; i < 4; ++i)
            af[i] = *(const short8*)(As + (wm + i * 16 + l15) * LDA + quad * 8);
#pragma unroll
        for (int j = 0; j < 4; ++j)
            bf[j] = *(const short8*)(Bs + (wn + j * 16 + l15) * LDA + quad * 8);
#pragma unroll
        for (int i = 0; i < 4; ++i)
#pragma unroll
            for (int j = 0; j < 4; ++j)
                acc[i][j] = __builtin_amdgcn_mfma_f32_16x16x32_bf16(
                    af[i], bf[j], acc[i][j], 0, 0, 0);
        __syncthreads();
    }

#pragma unroll
    for (int i = 0; i < 4; ++i)
#pragma unroll
        for (int j = 0; j < 4; ++j)
#pragma unroll
            for (int r = 0; r < 4; ++r) {
                int m = m0 + wm + i * 16 + quad * 4 + r;
                int n = n0 + wn + j * 16 + l15;
                gi[(size_t)m * G3 + n] = f2bf(acc[i][j][r] + bias[j]);
            }
}

// ---------------------------------------------------------------------------
// Kernel 2: persistent recurrence with per-producer flag slots.
// 128 blocks = 64 jg (16 h-cols) x 2 mt (16 batch rows); 512 thr = 8 waves,
// wave = K-slice of 128. W_hh hi/lo frags in registers for all 512 steps.
//
// Sync protocol (the round-2 spin was a contended acquire-RMW storm):
//  producer: plain h stores -> release fence (wave0) -> relaxed store
//            flag[jg] = t+1 (own slot, no RMW).
//  consumer: ONLY wave0 spins; lane i relaxed-loads flag[i] (one coalesced
//            dword load, no per-poll invalidate), exits on __all(>= t);
//            then __syncthreads; then one acquire fence; then h loads.
// ---------------------------------------------------------------------------
__global__ __launch_bounds__(512, 2) void gru_rec(
    const unsigned short* __restrict__ gi,
    const unsigned short* __restrict__ whh_h,
    const unsigned short* __restrict__ whh_l,
    const float* __restrict__ bias_hh,
    unsigned short* __restrict__ hbuf,  // [2][2][32][1024]
    int* __restrict__ cnt,              // [2][64] flags
    float* __restrict__ out) {
    __shared__ floatx4 parts[8][3][64];  // 24 KB

    int jg = blockIdx.x >> 1, mt = blockIdx.x & 1;
    int tid = threadIdx.x;
    int ks = tid >> 6, lane = tid & 63;
    int quad = lane >> 4, l15 = lane & 15;
    int j = jg * 16 + l15;

    // preload W_hh fragments (hi+lo): 3 gates x 4 ksteps x 16B = 96 VGPRs
    short8 wfh[3][4], wfl[3][4];
#pragma unroll
    for (int g = 0; g < 3; ++g)
#pragma unroll
        for (int ki = 0; ki < 4; ++ki) {
            size_t off = (size_t)(g * H_ + j) * H_ + ks * 128 + ki * 32 + quad * 8;
            wfh[g][ki] = *(const short8*)(whh_h + off);
            wfl[g][ki] = *(const short8*)(whh_l + off);
        }

    float bhh[3] = {0.f, 0.f, 0.f};
    float hreg[4] = {0.f, 0.f, 0.f, 0.f};
    if (ks == 0) {
#pragma unroll
        for (int g = 0; g < 3; ++g) bhh[g] = bias_hh[g * H_ + j];
    }

    const int arow = mt * 16 + l15;
    const int kbase = ks * 128 + quad * 8;
    int* const cbase = cnt + mt * 64;   // this mt group's 64 flag slots

    for (int t = 0; t < S_; ++t) {
        // gi prefetch (wave0) — read-only data, safe before the sync
        unsigned short giu[3][4];
        if (ks == 0) {
#pragma unroll
            for (int g = 0; g < 3; ++g)
#pragma unroll
                for (int r = 0; r < 4; ++r) {
                    int b = mt * 16 + quad * 4 + r;
                    giu[g][r] = gi[((size_t)b * S_ + t) * G3 + g * H_ + j];
                }
        }

        if (t > 0) {
            if (ks == 0) {  // lane i polls producer i's slot, relaxed
                int v = __hip_atomic_load(cbase + lane, __ATOMIC_RELAXED,
                                          __HIP_MEMORY_SCOPE_AGENT);
                while (!__all(v >= t)) {
                    __builtin_amdgcn_s_sleep(2);
                    v = __hip_atomic_load(cbase + lane, __ATOMIC_RELAXED,
                                          __HIP_MEMORY_SCOPE_AGENT);
                }
            }
            __syncthreads();
            // one invalidate per wave per step, not per poll
            __builtin_amdgcn_fence(__ATOMIC_ACQUIRE, "agent");
        }

        const unsigned short* hc = hbuf + (size_t)(t & 1) * 65536;
        unsigned short* hn = hbuf + (size_t)((t & 1) ^ 1) * 65536;

        short8 ah[4], al[4];
#pragma unroll
        for (int ki = 0; ki < 4; ++ki) {
            const unsigned short* p = hc + arow * H_ + kbase + ki * 32;
            ah[ki] = *(const short8*)(p);
            al[ki] = *(const short8*)(p + 32768);
        }

        floatx4 acc[3];
#pragma unroll
        for (int g = 0; g < 3; ++g) acc[g] = (floatx4){0.f, 0.f, 0.f, 0.f};
#pragma unroll
        for (int ki = 0; ki < 4; ++ki)
#pragma unroll
            for (int g = 0; g < 3; ++g) {
                acc[g] = __builtin_amdgcn_mfma_f32_16x16x32_bf16(ah[ki], wfh[g][ki], acc[g], 0, 0, 0);
                acc[g] = __builtin_amdgcn_mfma_f32_16x16x32_bf16(ah[ki], wfl[g][ki], acc[g], 0, 0, 0);
                acc[g] = __builtin_amdgcn_mfma_f32_16x16x32_bf16(al[ki], wfh[g][ki], acc[g], 0, 0, 0);
            }
#pragma unroll
        for (int g = 0; g < 3; ++g) parts[ks][g][lane] = acc[g];
        __syncthreads();
        // waves 1..7 proceed to t+1; their spin includes OUR flag slot, which
        // wave0 sets only after consuming `parts` — LDS reuse is safe.

        float hy[4];
        if (ks == 0) {
            floatx4 gh[3];
#pragma unroll
            for (int g = 0; g < 3; ++g) {
                floatx4 s = parts[0][g][lane];
#pragma unroll
                for (int w = 1; w < 8; ++w) s += parts[w][g][lane];
                gh[g] = s;
            }
#pragma unroll
            for (int r = 0; r < 4; ++r) {
                int b = mt * 16 + quad * 4 + r;
                float rg = fsigmoid(bf2f(giu[0][r]) + gh[0][r] + bhh[0]);
                float zg = fsigmoid(bf2f(giu[1][r]) + gh[1][r] + bhh[1]);
                float ng = ftanh(bf2f(giu[2][r]) + rg * (gh[2][r] + bhh[2]));
                float h = ng + zg * (hreg[r] - ng);
                hreg[r] = h;
                hy[r] = h;
                unsigned short hh = f2bf(h);
                hn[b * H_ + j] = hh;
                hn[32768 + b * H_ + j] = f2bf(h - bf2f(hh));
            }
            // release: drain h stores (dirty L2 set is tiny; `out` is NT)
            __builtin_amdgcn_fence(__ATOMIC_RELEASE, "agent");
            if (tid == 0)
                __hip_atomic_store(cbase + jg, t + 1, __ATOMIC_RELAXED,
                                   __HIP_MEMORY_SCOPE_AGENT);
            // out stores off the critical path, nontemporal (keep L2 clean)
#pragma unroll
            for (int r = 0; r < 4; ++r) {
                int b = mt * 16 + quad * 4 + r;
                __builtin_nontemporal_store(hy[r], out + ((size_t)b * S_ + t) * H_ + j);
                if (t == S_ - 1)
                    __builtin_nontemporal_store(hy[r], out + (size_t)B_ * S_ * H_ + (size_t)b * H_ + j);
            }
        }
    }
}

// ---------------------------------------------------------------------------
extern "C" void kernel_launch(void* const* d_in, const int* in_sizes, int n_in,
                              void* d_out, int out_size, void* d_ws, size_t ws_size,
                              hipStream_t stream) {
    const float* feats = (const float*)d_in[0];
    const float* wih   = (const float*)d_in[1];
    const float* whh   = (const float*)d_in[2];
    const float* bih   = (const float*)d_in[3];
    const float* bhh   = (const float*)d_in[4];
    float* out = (float*)d_out;

    // ws layout (ushorts): wih_h | whh_h | whh_l | gi | hbuf | cnt
    unsigned short* wih_h = (unsigned short*)d_ws;
    unsigned short* whh_h = wih_h + (size_t)3145728;
    unsigned short* whh_l = whh_h + (size_t)3145728;
    unsigned short* gi    = whh_l + (size_t)3145728;
    unsigned short* hbuf  = gi + (size_t)16384 * G3;
    int*            cnt   = (int*)(hbuf + 131072);

    hipLaunchKernelGGL(convert_kernel, dim3(3072), dim3(256), 0, stream,
                       wih, whh, wih_h, whh_h, whh_l, hbuf, cnt);
    hipLaunchKernelGGL(gi_gemm, dim3(3072), dim3(256), 0, stream,
                       feats, wih_h, bih, gi);

    void* args[] = {(void*)&gi, (void*)&whh_h, (void*)&whh_l,
                    (void*)&bhh, (void*)&hbuf, (void*)&cnt, (void*)&out};
    hipLaunchCooperativeKernel((const void*)gru_rec, dim3(128), dim3(512),
                               args, 0, stream);
}

// Round 4
// 3457.177 us; speedup vs baseline: 5.4817x; 2.3836x over previous
//
#include <hip/hip_runtime.h>

// GRU: B=32, S=512, D=1024, H=1024
// out = concat(output[B,S,H], h_last[B,H]) f32
#define B_  32
#define S_  512
#define D_  1024
#define H_  1024
#define G3  3072

typedef __attribute__((ext_vector_type(8))) short  short8;   // 8 x bf16 (4 VGPR)
typedef __attribute__((ext_vector_type(4))) float  floatx4;  // MFMA C/D

__device__ __forceinline__ unsigned short f2bf(float f) {
    unsigned int u = __builtin_bit_cast(unsigned int, f);
    u = (u + 0x7FFFu + ((u >> 16) & 1u)) >> 16;
    return (unsigned short)u;
}
__device__ __forceinline__ float bf2f(unsigned short h) {
    unsigned int u = ((unsigned int)h) << 16;
    return __builtin_bit_cast(float, u);
}
// fast sigmoid/tanh via v_exp_f32 + v_rcp_f32 (saturate correctly at +/-inf)
__device__ __forceinline__ float fsigmoid(float x) {
    float e = __builtin_amdgcn_exp2f(-1.4426950408889634f * x);
    return __builtin_amdgcn_rcpf(1.f + e);
}
__device__ __forceinline__ float ftanh(float x) {
    float e = __builtin_amdgcn_exp2f(2.8853900817779268f * x);
    return 1.f - 2.f * __builtin_amdgcn_rcpf(e + 1.f);
}

// ---------------------------------------------------------------------------
// Kernel 0: convert weights f32->bf16 (W_hh hi/lo split), zero h + flags
// ---------------------------------------------------------------------------
__global__ __launch_bounds__(256) void convert_kernel(
    const float* __restrict__ wih, const float* __restrict__ whh,
    unsigned short* __restrict__ wih_h,
    unsigned short* __restrict__ whh_h, unsigned short* __restrict__ whh_l,
    unsigned int* __restrict__ hbuf /* 65536 uints: 2 ping-pong x 32 x 1024 */,
    int* __restrict__ cnt /* 128 ints: [mt][jg] flags */) {
    int tid = blockIdx.x * 256 + threadIdx.x;   // 786432 threads
    int i4 = tid * 4;
    if (i4 < 3145728) {
        float4 w = *(const float4*)(wih + i4);
        ushort4 o;
        o.x = f2bf(w.x); o.y = f2bf(w.y); o.z = f2bf(w.z); o.w = f2bf(w.w);
        *(ushort4*)(wih_h + i4) = o;

        float4 v = *(const float4*)(whh + i4);
        ushort4 h;
        h.x = f2bf(v.x); h.y = f2bf(v.y); h.z = f2bf(v.z); h.w = f2bf(v.w);
        ushort4 l;
        l.x = f2bf(v.x - bf2f(h.x)); l.y = f2bf(v.y - bf2f(h.y));
        l.z = f2bf(v.z - bf2f(h.z)); l.w = f2bf(v.w - bf2f(h.w));
        *(ushort4*)(whh_h + i4) = h;
        *(ushort4*)(whh_l + i4) = l;
    }
    if (tid < 16384) {  // zero both packed h ping-pong buffers
        uint4 z; z.x = z.y = z.z = z.w = 0;
        *(uint4*)(hbuf + tid * 4) = z;
    }
    if (tid < 32) {     // zero the 128 per-producer step flags
        int4 z4; z4.x = z4.y = z4.z = z4.w = 0;
        *(int4*)(cnt + tid * 4) = z4;
    }
}

// ---------------------------------------------------------------------------
// Kernel 1: gi = feats @ W_ih^T + bias_ih   -> bf16 [B*S][3H]
// 128x128 tile, BK=32, 4 waves 2x2, mfma_f32_16x16x32_bf16
// ---------------------------------------------------------------------------
#define BM 128
#define BN 128
#define BK 32
#define LDA 40  // padded LDS row: 80B stride -> conflict-free b128 reads

__global__ __launch_bounds__(256, 2) void gi_gemm(
    const float* __restrict__ feats,
    const unsigned short* __restrict__ wih_h,
    const float* __restrict__ bias_ih,
    unsigned short* __restrict__ gi) {
    __shared__ unsigned short As[BM * LDA];
    __shared__ unsigned short Bs[BN * LDA];

    int bx = blockIdx.x;
    int nb = bx % (G3 / BN);          // 24
    int mb = bx / (G3 / BN);          // 128
    int m0 = mb * BM, n0 = nb * BN;
    int tid = threadIdx.x;
    int lane = tid & 63, wave = tid >> 6;
    int quad = lane >> 4, l15 = lane & 15;
    int wm = (wave >> 1) * 64, wn = (wave & 1) * 64;

    floatx4 acc[4][4];
#pragma unroll
    for (int i = 0; i < 4; ++i)
#pragma unroll
        for (int j = 0; j < 4; ++j) acc[i][j] = (floatx4){0.f, 0.f, 0.f, 0.f};

    float bias[4];
#pragma unroll
    for (int j = 0; j < 4; ++j) bias[j] = bias_ih[n0 + wn + j * 16 + l15];

    int srow = tid >> 1, shalf = tid & 1;
    const float* aptr = feats + (size_t)(m0 + srow) * D_ + shalf * 16;
    const unsigned short* bptr = wih_h + (size_t)(n0 + srow) * D_ + shalf * 16;
    unsigned short* as = As + srow * LDA + shalf * 16;
    unsigned short* bs = Bs + srow * LDA + shalf * 16;

    for (int kt = 0; kt < D_ / BK; ++kt) {
        int k0 = kt * BK;
        float4 a0 = *(const float4*)(aptr + k0);
        float4 a1 = *(const float4*)(aptr + k0 + 4);
        float4 a2 = *(const float4*)(aptr + k0 + 8);
        float4 a3 = *(const float4*)(aptr + k0 + 12);
        uint4 bA = *(const uint4*)(bptr + k0);
        uint4 bB = *(const uint4*)(bptr + k0 + 8);

        union { unsigned short u16[16]; uint4 v[2]; } pk;
        pk.u16[0] = f2bf(a0.x);  pk.u16[1] = f2bf(a0.y);
        pk.u16[2] = f2bf(a0.z);  pk.u16[3] = f2bf(a0.w);
        pk.u16[4] = f2bf(a1.x);  pk.u16[5] = f2bf(a1.y);
        pk.u16[6] = f2bf(a1.z);  pk.u16[7] = f2bf(a1.w);
        pk.u16[8] = f2bf(a2.x);  pk.u16[9] = f2bf(a2.y);
        pk.u16[10] = f2bf(a2.z); pk.u16[11] = f2bf(a2.w);
        pk.u16[12] = f2bf(a3.x); pk.u16[13] = f2bf(a3.y);
        pk.u16[14] = f2bf(a3.z); pk.u16[15] = f2bf(a3.w);

        *(uint4*)as = pk.v[0];
        *(uint4*)(as + 8) = pk.v[1];
        *(uint4*)bs = bA;
        *(uint4*)(bs + 8) = bB;
        __syncthreads();

        short8 af[4], bf[4];
#pragma unroll
        for (int i = 0; i < 4; ++i)
            af[i] = *(const short8*)(As + (wm + i * 16 + l15) * LDA + quad * 8);
#pragma unroll
        for (int j = 0; j < 4; ++j)
            bf[j] = *(const short8*)(Bs + (wn + j * 16 + l15) * LDA + quad * 8);
#pragma unroll
        for (int i = 0; i < 4; ++i)
#pragma unroll
            for (int j = 0; j < 4; ++j)
                acc[i][j] = __builtin_amdgcn_mfma_f32_16x16x32_bf16(
                    af[i], bf[j], acc[i][j], 0, 0, 0);
        __syncthreads();
    }

#pragma unroll
    for (int i = 0; i < 4; ++i)
#pragma unroll
        for (int j = 0; j < 4; ++j)
#pragma unroll
            for (int r = 0; r < 4; ++r) {
                int m = m0 + wm + i * 16 + quad * 4 + r;
                int n = n0 + wn + j * 16 + l15;
                gi[(size_t)m * G3 + n] = f2bf(acc[i][j][r] + bias[j]);
            }
}

// ---------------------------------------------------------------------------
// Kernel 2: persistent recurrence — NO cache-maintenance ops in the loop.
// 128 blocks = 64 jg (16 h-cols) x 2 mt (16 batch rows); 512 thr = 8 waves.
// h exchange + flags use relaxed AGENT-scope atomics (sc-bit coherent
// loads/stores straight to Infinity Cache; no buffer_inv / buffer_wbl2).
// h is packed: u32 = hi_bf16 | (lo_bf16 << 16).
// Producer order: h atomic-stores -> s_waitcnt vmcnt(0) -> flag store.
// Consumer order: wave0 polls flags -> __syncthreads (compiler barrier,
//                 blocks hoisting) -> h atomic-loads.
// ---------------------------------------------------------------------------
__global__ __launch_bounds__(512, 2) void gru_rec(
    const unsigned short* __restrict__ gi,
    const unsigned short* __restrict__ whh_h,
    const unsigned short* __restrict__ whh_l,
    const float* __restrict__ bias_hh,
    unsigned int* __restrict__ hbuf,    // [2][32][1024] packed hi|lo
    int* __restrict__ cnt,              // [2][64] flags
    float* __restrict__ out) {
    __shared__ floatx4 parts[8][3][64];  // 24 KB

    int jg = blockIdx.x >> 1, mt = blockIdx.x & 1;
    int tid = threadIdx.x;
    int ks = tid >> 6, lane = tid & 63;
    int quad = lane >> 4, l15 = lane & 15;
    int j = jg * 16 + l15;

    // preload W_hh fragments (hi+lo): 3 gates x 4 ksteps x 16B = 96 VGPRs
    short8 wfh[3][4], wfl[3][4];
#pragma unroll
    for (int g = 0; g < 3; ++g)
#pragma unroll
        for (int ki = 0; ki < 4; ++ki) {
            size_t off = (size_t)(g * H_ + j) * H_ + ks * 128 + ki * 32 + quad * 8;
            wfh[g][ki] = *(const short8*)(whh_h + off);
            wfl[g][ki] = *(const short8*)(whh_l + off);
        }

    float bhh[3] = {0.f, 0.f, 0.f};
    float hreg[4] = {0.f, 0.f, 0.f, 0.f};
    if (ks == 0) {
#pragma unroll
        for (int g = 0; g < 3; ++g) bhh[g] = bias_hh[g * H_ + j];
    }

    const int arow = mt * 16 + l15;
    const int kbase = ks * 128 + quad * 8;   // uint-col within row of 1024
    int* const cbase = cnt + mt * 64;        // this mt group's 64 flag slots

    for (int t = 0; t < S_; ++t) {
        // gi prefetch (wave0) — read-only data, safe before the sync
        unsigned short giu[3][4];
        if (ks == 0) {
#pragma unroll
            for (int g = 0; g < 3; ++g)
#pragma unroll
                for (int r = 0; r < 4; ++r) {
                    int b = mt * 16 + quad * 4 + r;
                    giu[g][r] = gi[((size_t)b * S_ + t) * G3 + g * H_ + j];
                }
        }

        if (t > 0) {
            if (ks == 0) {  // lane i polls producer i's slot, relaxed agent
                int v = __hip_atomic_load(cbase + lane, __ATOMIC_RELAXED,
                                          __HIP_MEMORY_SCOPE_AGENT);
                while (!__all(v >= t)) {
                    __builtin_amdgcn_s_sleep(1);
                    v = __hip_atomic_load(cbase + lane, __ATOMIC_RELAXED,
                                          __HIP_MEMORY_SCOPE_AGENT);
                }
            }
            __syncthreads();   // orders h loads after the poll; no fence
        }

        const unsigned int* hc = hbuf + ((t & 1) << 15);
        unsigned int* hn = hbuf + (((t & 1) ^ 1) << 15);

        // h fragments via relaxed agent b64 loads (bypass stale caches)
        short8 ah[4], al[4];
#pragma unroll
        for (int ki = 0; ki < 4; ++ki) {
            const unsigned long long* p =
                (const unsigned long long*)(hc + arow * H_ + kbase + ki * 32);
            unsigned long long q[4];
#pragma unroll
            for (int c = 0; c < 4; ++c)
                q[c] = __hip_atomic_load(p + c, __ATOMIC_RELAXED,
                                         __HIP_MEMORY_SCOPE_AGENT);
            short8 av, lv;
#pragma unroll
            for (int c = 0; c < 4; ++c) {
                unsigned int u0 = (unsigned int)q[c];
                unsigned int u1 = (unsigned int)(q[c] >> 32);
                av[2 * c]     = (short)(u0 & 0xffffu);
                av[2 * c + 1] = (short)(u1 & 0xffffu);
                lv[2 * c]     = (short)(u0 >> 16);
                lv[2 * c + 1] = (short)(u1 >> 16);
            }
            ah[ki] = av;
            al[ki] = lv;
        }

        floatx4 acc[3];
#pragma unroll
        for (int g = 0; g < 3; ++g) acc[g] = (floatx4){0.f, 0.f, 0.f, 0.f};
#pragma unroll
        for (int ki = 0; ki < 4; ++ki)
#pragma unroll
            for (int g = 0; g < 3; ++g) {
                acc[g] = __builtin_amdgcn_mfma_f32_16x16x32_bf16(ah[ki], wfh[g][ki], acc[g], 0, 0, 0);
                acc[g] = __builtin_amdgcn_mfma_f32_16x16x32_bf16(ah[ki], wfl[g][ki], acc[g], 0, 0, 0);
                acc[g] = __builtin_amdgcn_mfma_f32_16x16x32_bf16(al[ki], wfh[g][ki], acc[g], 0, 0, 0);
            }
#pragma unroll
        for (int g = 0; g < 3; ++g) parts[ks][g][lane] = acc[g];
        __syncthreads();
        // waves 1..7 proceed to t+1; their progress is gated by the flag,
        // which wave0 sets only after consuming `parts` — LDS reuse safe.

        float hy[4];
        if (ks == 0) {
            floatx4 gh[3];
#pragma unroll
            for (int g = 0; g < 3; ++g) {
                floatx4 s = parts[0][g][lane];
#pragma unroll
                for (int w = 1; w < 8; ++w) s += parts[w][g][lane];
                gh[g] = s;
            }
#pragma unroll
            for (int r = 0; r < 4; ++r) {
                int b = mt * 16 + quad * 4 + r;
                float rg = fsigmoid(bf2f(giu[0][r]) + gh[0][r] + bhh[0]);
                float zg = fsigmoid(bf2f(giu[1][r]) + gh[1][r] + bhh[1]);
                float ng = ftanh(bf2f(giu[2][r]) + rg * (gh[2][r] + bhh[2]));
                float h = ng + zg * (hreg[r] - ng);
                hreg[r] = h;
                hy[r] = h;
                unsigned short hh = f2bf(h);
                unsigned int pk = (unsigned int)hh |
                                  ((unsigned int)f2bf(h - bf2f(hh)) << 16);
                __hip_atomic_store(hn + b * H_ + j, pk, __ATOMIC_RELAXED,
                                   __HIP_MEMORY_SCOPE_AGENT);
            }
            // order: h stores globally visible before the flag store
            asm volatile("s_waitcnt vmcnt(0)" ::: "memory");
            if (tid == 0)
                __hip_atomic_store(cbase + jg, t + 1, __ATOMIC_RELAXED,
                                   __HIP_MEMORY_SCOPE_AGENT);
            // out stores off the critical path, nontemporal
#pragma unroll
            for (int r = 0; r < 4; ++r) {
                int b = mt * 16 + quad * 4 + r;
                __builtin_nontemporal_store(hy[r], out + ((size_t)b * S_ + t) * H_ + j);
                if (t == S_ - 1)
                    __builtin_nontemporal_store(hy[r], out + (size_t)B_ * S_ * H_ + (size_t)b * H_ + j);
            }
        }
    }
}

// ---------------------------------------------------------------------------
extern "C" void kernel_launch(void* const* d_in, const int* in_sizes, int n_in,
                              void* d_out, int out_size, void* d_ws, size_t ws_size,
                              hipStream_t stream) {
    const float* feats = (const float*)d_in[0];
    const float* wih   = (const float*)d_in[1];
    const float* whh   = (const float*)d_in[2];
    const float* bih   = (const float*)d_in[3];
    const float* bhh   = (const float*)d_in[4];
    float* out = (float*)d_out;

    // ws layout (ushorts): wih_h | whh_h | whh_l | gi | hbuf(u32) | cnt
    unsigned short* wih_h = (unsigned short*)d_ws;
    unsigned short* whh_h = wih_h + (size_t)3145728;
    unsigned short* whh_l = whh_h + (size_t)3145728;
    unsigned short* gi    = whh_l + (size_t)3145728;
    unsigned int*   hbuf  = (unsigned int*)(gi + (size_t)16384 * G3);
    int*            cnt   = (int*)(hbuf + 65536);

    hipLaunchKernelGGL(convert_kernel, dim3(3072), dim3(256), 0, stream,
                       wih, whh, wih_h, whh_h, whh_l, hbuf, cnt);
    hipLaunchKernelGGL(gi_gemm, dim3(3072), dim3(256), 0, stream,
                       feats, wih_h, bih, gi);

    void* args[] = {(void*)&gi, (void*)&whh_h, (void*)&whh_l,
                    (void*)&bhh, (void*)&hbuf, (void*)&cnt, (void*)&out};
    hipLaunchCooperativeKernel((const void*)gru_rec, dim3(128), dim3(512),
                               args, 0, stream);
}